// Round 5
// baseline (447.876 us; speedup 1.0000x reference)
//
#include <hip/hip_runtime.h>
#include <hip/hip_bf16.h>

#define NN 8192
#define FF 64
#define JSPLIT 4
#define JRANGE (NN / JSPLIT)    // 2048 cols per block (4 waves x 512)
#define PROW 66                 // partial row stride (floats): H[0..63], l at [64]
#define MROW (NN / 8)           // mask bytes per row (1024)

typedef _Float16 half8 __attribute__((ext_vector_type(8)));
typedef _Float16 half4v __attribute__((ext_vector_type(4)));
typedef float f32x4 __attribute__((ext_vector_type(4)));
typedef float f32x4v __attribute__((ext_vector_type(4)));
typedef int i32x4 __attribute__((ext_vector_type(4)));

// ---------------------------------------------------------------------------
// Kernel 0: bit-pack adj (256 MB int32 0/1) -> mask (8 MB, bit j of byte =
// adj[..*8+j]>0). Pure streaming: 32 B/thread coalesced reads, byte store.
// ---------------------------------------------------------------------------
__global__ __launch_bounds__(256) void k_pack(const int* __restrict__ adj,
                                              unsigned char* __restrict__ mask)
{
    const size_t idx = (size_t)blockIdx.x * 256 + threadIdx.x;   // byte index
    const i32x4* p = (const i32x4*)adj + idx * 2;
    i32x4 a = __builtin_nontemporal_load(p);
    i32x4 b = __builtin_nontemporal_load(p + 1);
    unsigned v = 0;
    v |= (a[0] > 0) ? 1u   : 0u;
    v |= (a[1] > 0) ? 2u   : 0u;
    v |= (a[2] > 0) ? 4u   : 0u;
    v |= (a[3] > 0) ? 8u   : 0u;
    v |= (b[0] > 0) ? 16u  : 0u;
    v |= (b[1] > 0) ? 32u  : 0u;
    v |= (b[2] > 0) ? 64u  : 0u;
    v |= (b[3] > 0) ? 128u : 0u;
    mask[idx] = (unsigned char)v;
}

// ---------------------------------------------------------------------------
// Kernel 1: Wh = inputs @ W; s = Wh@a_src; d = Wh@a_dst; WhT fp16 (80 x NN:
// rows 0..63 = Wh^T, row 64 = ones, 65..79 = 0); per-block max(d) partial.
// ---------------------------------------------------------------------------
__global__ __launch_bounds__(256) void k_prep(const float* __restrict__ inp,
                                              const float* __restrict__ W,
                                              const float* __restrict__ a,
                                              _Float16* __restrict__ WhT,
                                              float* __restrict__ s,
                                              float* __restrict__ d,
                                              float* __restrict__ dmax_part)
{
    __shared__ float Wl[64][64];
    __shared__ float asrc[64], adst[64];
    __shared__ _Float16 tr[64][20];
    __shared__ float dmx[16];
    const int t = threadIdx.x;
    for (int idx = t; idx < 4096; idx += 256) Wl[idx >> 6][idx & 63] = W[idx];
    if (t < 64) { asrc[t] = a[t]; adst[t] = a[64 + t]; }
    __syncthreads();

    const int rowl = t >> 4;
    const int fg   = t & 15;
    const int row  = blockIdx.x * 16 + rowl;
    const float* ip = inp + (size_t)row * FF;

    float a0 = 0.f, a1 = 0.f, a2 = 0.f, a3 = 0.f;
    #pragma unroll
    for (int k4 = 0; k4 < 16; ++k4) {
        float4 x  = *(const float4*)(ip + k4 * 4);
        float4 w0 = *(const float4*)&Wl[k4 * 4 + 0][fg * 4];
        float4 w1 = *(const float4*)&Wl[k4 * 4 + 1][fg * 4];
        float4 w2 = *(const float4*)&Wl[k4 * 4 + 2][fg * 4];
        float4 w3 = *(const float4*)&Wl[k4 * 4 + 3][fg * 4];
        a0 += x.x * w0.x + x.y * w1.x + x.z * w2.x + x.w * w3.x;
        a1 += x.x * w0.y + x.y * w1.y + x.z * w2.y + x.w * w3.y;
        a2 += x.x * w0.z + x.y * w1.z + x.z * w2.z + x.w * w3.z;
        a3 += x.x * w0.w + x.y * w1.w + x.z * w2.w + x.w * w3.w;
    }

    float sp = a0 * asrc[fg*4] + a1 * asrc[fg*4+1] + a2 * asrc[fg*4+2] + a3 * asrc[fg*4+3];
    float dp = a0 * adst[fg*4] + a1 * adst[fg*4+1] + a2 * adst[fg*4+2] + a3 * adst[fg*4+3];
    #pragma unroll
    for (int msk = 1; msk < 16; msk <<= 1) {
        sp += __shfl_xor(sp, msk);
        dp += __shfl_xor(dp, msk);
    }
    if (fg == 0) { s[row] = sp; d[row] = dp; dmx[rowl] = dp; }

    tr[fg * 4 + 0][rowl] = (_Float16)a0;
    tr[fg * 4 + 1][rowl] = (_Float16)a1;
    tr[fg * 4 + 2][rowl] = (_Float16)a2;
    tr[fg * 4 + 3][rowl] = (_Float16)a3;
    __syncthreads();
    {
        const int f = t >> 2, seg = t & 3;
        *(half4v*)(WhT + (size_t)f * NN + blockIdx.x * 16 + seg * 4) =
            *(const half4v*)&tr[f][seg * 4];
        const int fr = 64 + (t >> 4);
        WhT[(size_t)fr * NN + blockIdx.x * 16 + (t & 15)] =
            (_Float16)(((t >> 4) == 0) ? 1.0f : 0.0f);
    }
    if (t == 0) {
        float mm = dmx[0];
        #pragma unroll
        for (int i = 1; i < 16; ++i) mm = fmaxf(mm, dmx[i]);
        dmax_part[blockIdx.x] = mm;
    }
}

// ---------------------------------------------------------------------------
// Kernel 2: dmax = max over 512 partials; c[i] = leakyrelu(s[i] + dmax).
// ---------------------------------------------------------------------------
__global__ __launch_bounds__(256) void k_shift(const float* __restrict__ s,
                                               const float* __restrict__ dmax_part,
                                               float* __restrict__ c)
{
    __shared__ float red[256];
    const int t = threadIdx.x;
    float m = fmaxf(dmax_part[t], dmax_part[t + 256]);
    red[t] = m;
    __syncthreads();
    for (int off = 128; off > 0; off >>= 1) {
        if (t < off) red[t] = fmaxf(red[t], red[t + off]);
        __syncthreads();
    }
    const float dmax = red[0];
    const int row = blockIdx.x * 256 + t;
    float x = s[row] + dmax;
    c[row] = fmaxf(x, 0.2f * x);
}

// p_k = bit_k ? exp(leakyrelu(sv+d_k) - cv) : 0
__device__ __forceinline__ half4v build4(float sv, float cv, unsigned bits, f32x4v dd)
{
    half4v r;
    #pragma unroll
    for (int k = 0; k < 4; ++k) {
        float e = sv + dd[k];
        e = fmaxf(e, 0.2f * e);
        float p = ((bits >> k) & 1u) ? __expf(e - cv) : 0.0f;
        r[k] = (_Float16)p;
    }
    return r;
}

// ---------------------------------------------------------------------------
// Kernel 3 (main): 2048 blocks = 512 row-tiles x 4 j-splits; 4 waves per
// block own independent 16-row x 512-col strips. adj comes from the packed
// 8 MB mask (one uint2 per lane-group per iter, L2/L3-hit); dv/WhT from
// L2. No LDS staging, no K-loop barriers.
// ---------------------------------------------------------------------------
__global__ __launch_bounds__(256, 4) void k_main(const unsigned char* __restrict__ mask,
                                                 const _Float16* __restrict__ WhT,
                                                 const float* __restrict__ s,
                                                 const float* __restrict__ c,
                                                 const float* __restrict__ dv,
                                                 float* __restrict__ part)
{
    __shared__ float red[4][16][66];

    const int tid  = threadIdx.x;
    const int wv   = tid >> 6;
    const int lane = tid & 63;
    const int m    = lane & 15;
    const int g    = lane >> 4;
    const int rt   = blockIdx.x >> 2;
    const int js   = blockIdx.x & 3;
    const int i0   = rt * 16;
    const int row  = i0 + m;
    const int jw   = js * JRANGE + wv * 512 + g * 8;  // lane's starting col

    const float sv = s[row];
    const float cv = c[row];

    // mask: u64 (as uint2) covering this wave's 64-col window each iter;
    // all 4 g-lanes of a row load the same address (broadcast-friendly).
    const unsigned char* mp = mask + (size_t)row * MROW + (js * JRANGE + wv * 512) / 8;
    const float*    dp = dv + jw;
    const _Float16* bp = WhT + (size_t)m * NN + jw;

    f32x4 acc[5];
    #pragma unroll
    for (int n = 0; n < 5; ++n) acc[n] = (f32x4){0.f, 0.f, 0.f, 0.f};

    #pragma unroll
    for (int it = 0; it < 8; ++it) {
        uint2 mw = *(const uint2*)(mp + it * 8);
        const unsigned b0 = (mw.x >> (g * 8)) & 0xffu;   // cols [jb, jb+8)
        const unsigned b1 = (mw.y >> (g * 8)) & 0xffu;   // cols [jb+32, jb+40)

        f32x4v d0 = *(const f32x4v*)(dp + it * 64);
        f32x4v d1 = *(const f32x4v*)(dp + it * 64 + 4);
        f32x4v d2 = *(const f32x4v*)(dp + it * 64 + 32);
        f32x4v d3 = *(const f32x4v*)(dp + it * 64 + 36);

        half4v lo0 = build4(sv, cv, b0 & 15u, d0);
        half4v hi0 = build4(sv, cv, b0 >> 4,  d1);
        half4v lo1 = build4(sv, cv, b1 & 15u, d2);
        half4v hi1 = build4(sv, cv, b1 >> 4,  d3);
        half8 Af0 = __builtin_shufflevector(lo0, hi0, 0, 1, 2, 3, 4, 5, 6, 7);
        half8 Af1 = __builtin_shufflevector(lo1, hi1, 0, 1, 2, 3, 4, 5, 6, 7);

        const _Float16* bq = bp + it * 64;
        #pragma unroll
        for (int n = 0; n < 5; ++n) {
            half8 B0 = *(const half8*)(bq + (size_t)n * 16 * NN);
            half8 B1 = *(const half8*)(bq + (size_t)n * 16 * NN + 32);
            acc[n] = __builtin_amdgcn_mfma_f32_16x16x32_f16(Af0, B0, acc[n], 0, 0, 0);
            acc[n] = __builtin_amdgcn_mfma_f32_16x16x32_f16(Af1, B1, acc[n], 0, 0, 0);
        }
    }

    // ---- cross-wave combine into fp32 partial ----
    #pragma unroll
    for (int n = 0; n < 4; ++n)
        #pragma unroll
        for (int r = 0; r < 4; ++r)
            red[wv][g * 4 + r][n * 16 + m] = acc[n][r];
    if (m == 0) {
        #pragma unroll
        for (int r = 0; r < 4; ++r)
            red[wv][g * 4 + r][64] = acc[4][r];
    }
    __syncthreads();

    float* pb = part + (size_t)blockIdx.x * (16 * PROW);
    const int col = tid & 63;
    const int r0  = tid >> 6;
    #pragma unroll
    for (int rr = 0; rr < 4; ++rr) {
        const int rl = r0 * 4 + rr;
        pb[rl * PROW + col] = red[0][rl][col] + red[1][rl][col] +
                              red[2][rl][col] + red[3][rl][col];
    }
    if (tid < 16) {
        pb[tid * PROW + 64] = red[0][tid][64] + red[1][tid][64] +
                              red[2][tid][64] + red[3][tid][64];
    }
}

// ---------------------------------------------------------------------------
// Kernel 4: combine 4 j-split partials, divide by l, ELU, write out.
// ---------------------------------------------------------------------------
__global__ __launch_bounds__(256) void k_reduce(const float* __restrict__ part,
                                                float* __restrict__ out)
{
    const int rt  = blockIdx.x;
    const int col = threadIdx.x & 63;
    const int r0  = threadIdx.x >> 6;
    const float* pb = part + (size_t)rt * 4 * (16 * PROW);
    #pragma unroll
    for (int rr = 0; rr < 4; ++rr) {
        const int rl = r0 * 4 + rr;
        float h = 0.f, l = 0.f;
        #pragma unroll
        for (int j = 0; j < 4; ++j) {
            h += pb[(j * 16 + rl) * PROW + col];
            l += pb[(j * 16 + rl) * PROW + 64];
        }
        float v = h / l;
        out[(size_t)(rt * 16 + rl) * FF + col] = (v > 0.f) ? v : (__expf(v) - 1.0f);
    }
}

extern "C" void kernel_launch(void* const* d_in, const int* in_sizes, int n_in,
                              void* d_out, int out_size, void* d_ws, size_t ws_size,
                              hipStream_t stream)
{
    const float* inp = (const float*)d_in[0];
    const int*   adj = (const int*)d_in[1];
    const float* W   = (const float*)d_in[2];
    const float* a   = (const float*)d_in[3];
    float* out = (float*)d_out;

    char* ws = (char*)d_ws;
    _Float16* WhT = (_Float16*)ws;                           // 80*NN*2 = 1,310,720 B
    float* s    = (float*)(ws + (size_t)80 * NN * 2);        // 32 KB
    float* dv   = s + NN;                                    // 32 KB
    float* c    = dv + NN;                                   // 32 KB
    float* dmp  = c + NN;                                    // 512 floats
    float* part = dmp + 512;                                 // 2048*16*66*4 = 8.65 MB
    unsigned char* mask = (unsigned char*)(part + (size_t)2048 * 16 * PROW);  // 8 MB

    k_pack  <<<(NN / 8) * NN / 256, 256, 0, stream>>>(adj, mask);
    k_prep  <<<NN / 16, 256, 0, stream>>>(inp, W, a, WhT, s, dv, dmp);
    k_shift <<<32, 256, 0, stream>>>(s, dmp, c);
    k_main  <<<(NN / 16) * JSPLIT, 256, 0, stream>>>(mask, WhT, s, c, dv, part);
    k_reduce<<<NN / 16, 256, 0, stream>>>(part, out);
}

// Round 6
// 395.717 us; speedup vs baseline: 1.1318x; 1.1318x over previous
//
#include <hip/hip_runtime.h>
#include <hip/hip_bf16.h>

#define NN 8192
#define FF 64
#define JSPLIT 4
#define JRANGE (NN / JSPLIT)    // 2048 cols per block
#define JT 256                  // cols staged per iteration
#define NIT (JRANGE / JT)       // 8
#define TP 260                  // LDS adj tile row stride (ints), padded
#define PROW 66                 // partial row stride: H[0..63], l at [64]

typedef _Float16 half8 __attribute__((ext_vector_type(8)));
typedef _Float16 half4v __attribute__((ext_vector_type(4)));
typedef float f32x4 __attribute__((ext_vector_type(4)));
typedef float f32x4v __attribute__((ext_vector_type(4)));
typedef int i32x4 __attribute__((ext_vector_type(4)));

__device__ __forceinline__ void async16(const void* g, void* l)
{
    __builtin_amdgcn_global_load_lds(
        (const __attribute__((address_space(1))) unsigned int*)g,
        (__attribute__((address_space(3))) unsigned int*)l, 16, 0, 0);
}

// ---------------------------------------------------------------------------
// Kernel 1: Wh = inputs @ W; s = Wh@a_src; d = Wh@a_dst; WhT fp16 (80 x NN:
// rows 0..63 = Wh^T, row 64 = ones, 65..79 = 0); per-block max(d) partial.
// ---------------------------------------------------------------------------
__global__ __launch_bounds__(256) void k_prep(const float* __restrict__ inp,
                                              const float* __restrict__ W,
                                              const float* __restrict__ a,
                                              _Float16* __restrict__ WhT,
                                              float* __restrict__ s,
                                              float* __restrict__ d,
                                              float* __restrict__ dmax_part)
{
    __shared__ float Wl[64][64];
    __shared__ float asrc[64], adst[64];
    __shared__ _Float16 tr[64][20];
    __shared__ float dmx[16];
    const int t = threadIdx.x;
    for (int idx = t; idx < 4096; idx += 256) Wl[idx >> 6][idx & 63] = W[idx];
    if (t < 64) { asrc[t] = a[t]; adst[t] = a[64 + t]; }
    __syncthreads();

    const int rowl = t >> 4;
    const int fg   = t & 15;
    const int row  = blockIdx.x * 16 + rowl;
    const float* ip = inp + (size_t)row * FF;

    float a0 = 0.f, a1 = 0.f, a2 = 0.f, a3 = 0.f;
    #pragma unroll
    for (int k4 = 0; k4 < 16; ++k4) {
        float4 x  = *(const float4*)(ip + k4 * 4);
        float4 w0 = *(const float4*)&Wl[k4 * 4 + 0][fg * 4];
        float4 w1 = *(const float4*)&Wl[k4 * 4 + 1][fg * 4];
        float4 w2 = *(const float4*)&Wl[k4 * 4 + 2][fg * 4];
        float4 w3 = *(const float4*)&Wl[k4 * 4 + 3][fg * 4];
        a0 += x.x * w0.x + x.y * w1.x + x.z * w2.x + x.w * w3.x;
        a1 += x.x * w0.y + x.y * w1.y + x.z * w2.y + x.w * w3.y;
        a2 += x.x * w0.z + x.y * w1.z + x.z * w2.z + x.w * w3.z;
        a3 += x.x * w0.w + x.y * w1.w + x.z * w2.w + x.w * w3.w;
    }

    float sp = a0 * asrc[fg*4] + a1 * asrc[fg*4+1] + a2 * asrc[fg*4+2] + a3 * asrc[fg*4+3];
    float dp = a0 * adst[fg*4] + a1 * adst[fg*4+1] + a2 * adst[fg*4+2] + a3 * adst[fg*4+3];
    #pragma unroll
    for (int msk = 1; msk < 16; msk <<= 1) {
        sp += __shfl_xor(sp, msk);
        dp += __shfl_xor(dp, msk);
    }
    if (fg == 0) { s[row] = sp; d[row] = dp; dmx[rowl] = dp; }

    tr[fg * 4 + 0][rowl] = (_Float16)a0;
    tr[fg * 4 + 1][rowl] = (_Float16)a1;
    tr[fg * 4 + 2][rowl] = (_Float16)a2;
    tr[fg * 4 + 3][rowl] = (_Float16)a3;
    __syncthreads();
    {
        const int f = t >> 2, seg = t & 3;
        *(half4v*)(WhT + (size_t)f * NN + blockIdx.x * 16 + seg * 4) =
            *(const half4v*)&tr[f][seg * 4];
        const int fr = 64 + (t >> 4);
        WhT[(size_t)fr * NN + blockIdx.x * 16 + (t & 15)] =
            (_Float16)(((t >> 4) == 0) ? 1.0f : 0.0f);
    }
    if (t == 0) {
        float mm = dmx[0];
        #pragma unroll
        for (int i = 1; i < 16; ++i) mm = fmaxf(mm, dmx[i]);
        dmax_part[blockIdx.x] = mm;
    }
}

// ---------------------------------------------------------------------------
// Kernel 2: dmax = max over 512 partials; c[i] = leakyrelu(s[i] + dmax).
// ---------------------------------------------------------------------------
__global__ __launch_bounds__(256) void k_shift(const float* __restrict__ s,
                                               const float* __restrict__ dmax_part,
                                               float* __restrict__ c)
{
    __shared__ float red[256];
    const int t = threadIdx.x;
    float m = fmaxf(dmax_part[t], dmax_part[t + 256]);
    red[t] = m;
    __syncthreads();
    for (int off = 128; off > 0; off >>= 1) {
        if (t < off) red[t] = fmaxf(red[t], red[t + off]);
        __syncthreads();
    }
    const float dmax = red[0];
    const int row = blockIdx.x * 256 + t;
    float x = s[row] + dmax;
    c[row] = fmaxf(x, 0.2f * x);
}

__device__ __forceinline__ half4v build4(float sv, float cv, i32x4 aa, f32x4v dd)
{
    half4v r;
    #pragma unroll
    for (int k = 0; k < 4; ++k) {
        float e = sv + dd[k];
        e = fmaxf(e, 0.2f * e);
        float p = (aa[k] > 0) ? __expf(e - cv) : 0.0f;
        r[k] = (_Float16)p;
    }
    return r;
}

// ---------------------------------------------------------------------------
// Kernel 3 (main): 2048 blocks = 512 row-tiles x 4 j-splits. Block = 16 rows
// x 2048 cols, 8 iters of 256 cols double-buffered in LDS. Raw s_barrier +
// manual s_waitcnt vmcnt(4): each wave issues exactly 4 global_load_lds per
// stage, and the barrier does NOT drain the in-flight prefetch (AITER-style
// cross-barrier pipelining — __syncthreads would force vmcnt(0)).
// ---------------------------------------------------------------------------
__global__ __launch_bounds__(256, 3) void k_main(const int* __restrict__ adj,
                                                 const _Float16* __restrict__ WhT,
                                                 const float* __restrict__ s,
                                                 const float* __restrict__ c,
                                                 const float* __restrict__ dv,
                                                 float* __restrict__ part)
{
    __shared__ union __align__(16) {
        struct { int tile[2][16][TP]; float dvt[JRANGE]; } st;  // 33280+8192 B
        struct { float red[4][16][66]; } ep;                    // 16896 B
    } sm;

    const int tid  = threadIdx.x;
    const int wv   = tid >> 6;
    const int lane = tid & 63;
    const int m    = lane & 15;
    const int g    = lane >> 4;
    const int rt   = blockIdx.x >> 2;
    const int js   = blockIdx.x & 3;
    const int i0   = rt * 16;
    const int jq   = js * JRANGE;      // this block's column quarter
    const int row  = i0 + m;

    const float sv = s[row];
    const float cv = c[row];

    f32x4 acc[5];
    #pragma unroll
    for (int n = 0; n < 5; ++n) acc[n] = (f32x4){0.f, 0.f, 0.f, 0.f};

    // stage adj tile `it` (16 rows x 256 ints) into buffer b: 4 loads/wave
    auto stage = [&](int b, int it) {
        const int j0 = jq + it * JT;
        #pragma unroll
        for (int q = 0; q < 4; ++q) {
            const int r = wv * 4 + q;
            async16(adj + (size_t)(i0 + r) * NN + j0 + lane * 4,
                    &sm.st.tile[b][r][0]);
        }
    };

    // ---- prologue: dv quarter (8 KB) once + tile 0; full drain
    async16(dv + jq + (wv * 2 + 0) * 256 + lane * 4, &sm.st.dvt[(wv * 2 + 0) * 256]);
    async16(dv + jq + (wv * 2 + 1) * 256 + lane * 4, &sm.st.dvt[(wv * 2 + 1) * 256]);
    stage(0, 0);
    asm volatile("s_waitcnt vmcnt(0)" ::: "memory");
    __builtin_amdgcn_s_barrier();

    int buf = 0;
    for (int it = 0; it < NIT; ++it) {
        if (it + 1 < NIT) {
            stage(buf ^ 1, it + 1);                       // prefetch next tile
            asm volatile("s_waitcnt vmcnt(4)" ::: "memory");  // drain tile(it) only
        } else {
            asm volatile("s_waitcnt vmcnt(0)" ::: "memory");
        }
        __builtin_amdgcn_s_barrier();                     // tile(it) visible to all
        asm volatile("" ::: "memory");

        const int cb = wv * 64 + g * 8;                   // within 256-col tile
        const int cq = it * JT + cb;                      // within 2048-col quarter

        i32x4 A0 = *(const i32x4*)&sm.st.tile[buf][m][cb];
        i32x4 A1 = *(const i32x4*)&sm.st.tile[buf][m][cb + 4];
        i32x4 A2 = *(const i32x4*)&sm.st.tile[buf][m][cb + 32];
        i32x4 A3 = *(const i32x4*)&sm.st.tile[buf][m][cb + 36];
        f32x4v d0 = *(const f32x4v*)&sm.st.dvt[cq];
        f32x4v d1 = *(const f32x4v*)&sm.st.dvt[cq + 4];
        f32x4v d2 = *(const f32x4v*)&sm.st.dvt[cq + 32];
        f32x4v d3 = *(const f32x4v*)&sm.st.dvt[cq + 36];

        half4v lo0 = build4(sv, cv, A0, d0);
        half4v hi0 = build4(sv, cv, A1, d1);
        half4v lo1 = build4(sv, cv, A2, d2);
        half4v hi1 = build4(sv, cv, A3, d3);
        half8 Af0 = __builtin_shufflevector(lo0, hi0, 0, 1, 2, 3, 4, 5, 6, 7);
        half8 Af1 = __builtin_shufflevector(lo1, hi1, 0, 1, 2, 3, 4, 5, 6, 7);

        const _Float16* bq = WhT + (size_t)m * NN + jq + cq;
        #pragma unroll
        for (int n = 0; n < 5; ++n) {
            half8 B0 = *(const half8*)(bq + (size_t)n * 16 * NN);
            half8 B1 = *(const half8*)(bq + (size_t)n * 16 * NN + 32);
            acc[n] = __builtin_amdgcn_mfma_f32_16x16x32_f16(Af0, B0, acc[n], 0, 0, 0);
            acc[n] = __builtin_amdgcn_mfma_f32_16x16x32_f16(Af1, B1, acc[n], 0, 0, 0);
        }

        asm volatile("" ::: "memory");
        __builtin_amdgcn_s_barrier();    // all reads of buf done before overwrite
        buf ^= 1;
    }

    // ---- cross-wave combine into fp32 partial (reuses LDS via union) ----
    #pragma unroll
    for (int n = 0; n < 4; ++n)
        #pragma unroll
        for (int r = 0; r < 4; ++r)
            sm.ep.red[wv][g * 4 + r][n * 16 + m] = acc[n][r];
    if (m == 0) {
        #pragma unroll
        for (int r = 0; r < 4; ++r)
            sm.ep.red[wv][g * 4 + r][64] = acc[4][r];
    }
    __syncthreads();

    float* pb = part + (size_t)blockIdx.x * (16 * PROW);
    const int col = tid & 63;
    const int r0  = tid >> 6;
    #pragma unroll
    for (int rr = 0; rr < 4; ++rr) {
        const int rl = r0 * 4 + rr;
        pb[rl * PROW + col] = sm.ep.red[0][rl][col] + sm.ep.red[1][rl][col] +
                              sm.ep.red[2][rl][col] + sm.ep.red[3][rl][col];
    }
    if (tid < 16) {
        pb[tid * PROW + 64] = sm.ep.red[0][tid][64] + sm.ep.red[1][tid][64] +
                              sm.ep.red[2][tid][64] + sm.ep.red[3][tid][64];
    }
}

// ---------------------------------------------------------------------------
// Kernel 4: combine 4 j-split partials, divide by l, ELU, write out.
// ---------------------------------------------------------------------------
__global__ __launch_bounds__(256) void k_reduce(const float* __restrict__ part,
                                                float* __restrict__ out)
{
    const int rt  = blockIdx.x;
    const int col = threadIdx.x & 63;
    const int r0  = threadIdx.x >> 6;
    const float* pb = part + (size_t)rt * 4 * (16 * PROW);
    #pragma unroll
    for (int rr = 0; rr < 4; ++rr) {
        const int rl = r0 * 4 + rr;
        float h = 0.f, l = 0.f;
        #pragma unroll
        for (int j = 0; j < 4; ++j) {
            h += pb[(j * 16 + rl) * PROW + col];
            l += pb[(j * 16 + rl) * PROW + 64];
        }
        float v = h / l;
        out[(size_t)(rt * 16 + rl) * FF + col] = (v > 0.f) ? v : (__expf(v) - 1.0f);
    }
}

extern "C" void kernel_launch(void* const* d_in, const int* in_sizes, int n_in,
                              void* d_out, int out_size, void* d_ws, size_t ws_size,
                              hipStream_t stream)
{
    const float* inp = (const float*)d_in[0];
    const int*   adj = (const int*)d_in[1];
    const float* W   = (const float*)d_in[2];
    const float* a   = (const float*)d_in[3];
    float* out = (float*)d_out;

    char* ws = (char*)d_ws;
    _Float16* WhT = (_Float16*)ws;                           // 80*NN*2 = 1,310,720 B
    float* s    = (float*)(ws + (size_t)80 * NN * 2);        // 32 KB
    float* dv   = s + NN;                                    // 32 KB
    float* c    = dv + NN;                                   // 32 KB
    float* dmp  = c + NN;                                    // 512 floats
    float* part = dmp + 512;                                 // 2048*16*66*4 = 8.65 MB

    k_prep  <<<NN / 16, 256, 0, stream>>>(inp, W, a, WhT, s, dv, dmp);
    k_shift <<<32, 256, 0, stream>>>(s, dmp, c);
    k_main  <<<(NN / 16) * JSPLIT, 256, 0, stream>>>(adj, WhT, s, c, dv, part);
    k_reduce<<<NN / 16, 256, 0, stream>>>(part, out);
}

// Round 7
// 389.567 us; speedup vs baseline: 1.1497x; 1.0158x over previous
//
#include <hip/hip_runtime.h>
#include <hip/hip_bf16.h>

#define NN 8192
#define FF 64
#define JSPLIT 8
#define JRANGE (NN / JSPLIT)    // 1024 cols per block
#define JT 128                  // cols per iteration
#define NIT (JRANGE / JT)       // 8
#define PROW 66                 // partial row stride: H[0..63], l at [64]
#define MROW (NN / 8)           // mask bytes per row

// LDS layout per buffer (bytes)
#define B_OFF   0               // B tile: 64 feat-rows x 256 B (swizzled)
#define MK_OFF  16384           // mask tile: 64 rows x 16 B
#define DV_OFF  17408           // dv tile: 128 floats
#define DUP_OFF 17920           // dummy slot (uniform load count)
#define BUF_SZ  18944

typedef _Float16 half8 __attribute__((ext_vector_type(8)));
typedef _Float16 half4v __attribute__((ext_vector_type(4)));
typedef float f32x4 __attribute__((ext_vector_type(4)));
typedef float f32x4v __attribute__((ext_vector_type(4)));
typedef int i32x4 __attribute__((ext_vector_type(4)));

__device__ __forceinline__ void async16(const void* g, void* l)
{
    __builtin_amdgcn_global_load_lds(
        (const __attribute__((address_space(1))) unsigned int*)g,
        (__attribute__((address_space(3))) unsigned int*)l, 16, 0, 0);
}
__device__ __forceinline__ void async4(const void* g, void* l)
{
    __builtin_amdgcn_global_load_lds(
        (const __attribute__((address_space(1))) unsigned int*)g,
        (__attribute__((address_space(3))) unsigned int*)l, 4, 0, 0);
}

// ---------------------------------------------------------------------------
// Kernel 0: bit-pack adj (256 MB int32 0/1) -> mask (8 MB). Pure streaming.
// ---------------------------------------------------------------------------
__global__ __launch_bounds__(256) void k_pack(const int* __restrict__ adj,
                                              unsigned char* __restrict__ mask)
{
    const size_t idx = (size_t)blockIdx.x * 256 + threadIdx.x;   // byte index
    const i32x4* p = (const i32x4*)adj + idx * 2;
    i32x4 a = __builtin_nontemporal_load(p);
    i32x4 b = __builtin_nontemporal_load(p + 1);
    unsigned v = 0;
    v |= (a[0] > 0) ? 1u   : 0u;
    v |= (a[1] > 0) ? 2u   : 0u;
    v |= (a[2] > 0) ? 4u   : 0u;
    v |= (a[3] > 0) ? 8u   : 0u;
    v |= (b[0] > 0) ? 16u  : 0u;
    v |= (b[1] > 0) ? 32u  : 0u;
    v |= (b[2] > 0) ? 64u  : 0u;
    v |= (b[3] > 0) ? 128u : 0u;
    mask[idx] = (unsigned char)v;
}

// ---------------------------------------------------------------------------
// Kernel 1: Wh = inputs @ W; s = Wh@a_src; d = Wh@a_dst; WhT fp16 (rows
// 0..63 = Wh^T); per-block max(d) partial.
// ---------------------------------------------------------------------------
__global__ __launch_bounds__(256) void k_prep(const float* __restrict__ inp,
                                              const float* __restrict__ W,
                                              const float* __restrict__ a,
                                              _Float16* __restrict__ WhT,
                                              float* __restrict__ s,
                                              float* __restrict__ d,
                                              float* __restrict__ dmax_part)
{
    __shared__ float Wl[64][64];
    __shared__ float asrc[64], adst[64];
    __shared__ _Float16 tr[64][20];
    __shared__ float dmx[16];
    const int t = threadIdx.x;
    for (int idx = t; idx < 4096; idx += 256) Wl[idx >> 6][idx & 63] = W[idx];
    if (t < 64) { asrc[t] = a[t]; adst[t] = a[64 + t]; }
    __syncthreads();

    const int rowl = t >> 4;
    const int fg   = t & 15;
    const int row  = blockIdx.x * 16 + rowl;
    const float* ip = inp + (size_t)row * FF;

    float a0 = 0.f, a1 = 0.f, a2 = 0.f, a3 = 0.f;
    #pragma unroll
    for (int k4 = 0; k4 < 16; ++k4) {
        float4 x  = *(const float4*)(ip + k4 * 4);
        float4 w0 = *(const float4*)&Wl[k4 * 4 + 0][fg * 4];
        float4 w1 = *(const float4*)&Wl[k4 * 4 + 1][fg * 4];
        float4 w2 = *(const float4*)&Wl[k4 * 4 + 2][fg * 4];
        float4 w3 = *(const float4*)&Wl[k4 * 4 + 3][fg * 4];
        a0 += x.x * w0.x + x.y * w1.x + x.z * w2.x + x.w * w3.x;
        a1 += x.x * w0.y + x.y * w1.y + x.z * w2.y + x.w * w3.y;
        a2 += x.x * w0.z + x.y * w1.z + x.z * w2.z + x.w * w3.z;
        a3 += x.x * w0.w + x.y * w1.w + x.z * w2.w + x.w * w3.w;
    }

    float sp = a0 * asrc[fg*4] + a1 * asrc[fg*4+1] + a2 * asrc[fg*4+2] + a3 * asrc[fg*4+3];
    float dp = a0 * adst[fg*4] + a1 * adst[fg*4+1] + a2 * adst[fg*4+2] + a3 * adst[fg*4+3];
    #pragma unroll
    for (int msk = 1; msk < 16; msk <<= 1) {
        sp += __shfl_xor(sp, msk);
        dp += __shfl_xor(dp, msk);
    }
    if (fg == 0) { s[row] = sp; d[row] = dp; dmx[rowl] = dp; }

    tr[fg * 4 + 0][rowl] = (_Float16)a0;
    tr[fg * 4 + 1][rowl] = (_Float16)a1;
    tr[fg * 4 + 2][rowl] = (_Float16)a2;
    tr[fg * 4 + 3][rowl] = (_Float16)a3;
    __syncthreads();
    {
        const int f = t >> 2, seg = t & 3;
        *(half4v*)(WhT + (size_t)f * NN + blockIdx.x * 16 + seg * 4) =
            *(const half4v*)&tr[f][seg * 4];
    }
    if (t == 0) {
        float mm = dmx[0];
        #pragma unroll
        for (int i = 1; i < 16; ++i) mm = fmaxf(mm, dmx[i]);
        dmax_part[blockIdx.x] = mm;
    }
}

// ---------------------------------------------------------------------------
// Kernel 2: dmax = max over 512 partials; c[i] = leakyrelu(s[i] + dmax).
// ---------------------------------------------------------------------------
__global__ __launch_bounds__(256) void k_shift(const float* __restrict__ s,
                                               const float* __restrict__ dmax_part,
                                               float* __restrict__ c)
{
    __shared__ float red[256];
    const int t = threadIdx.x;
    float m = fmaxf(dmax_part[t], dmax_part[t + 256]);
    red[t] = m;
    __syncthreads();
    for (int off = 128; off > 0; off >>= 1) {
        if (t < off) red[t] = fmaxf(red[t], red[t + off]);
        __syncthreads();
    }
    const float dmax = red[0];
    const int row = blockIdx.x * 256 + t;
    float x = s[row] + dmax;
    c[row] = fmaxf(x, 0.2f * x);
}

// p_k = bit_k ? exp(leakyrelu(sv+d_k) - cv) : 0 ; accumulates fp16-rounded l
__device__ __forceinline__ half4v build4(float sv, float cv, unsigned bits,
                                         f32x4v dd, float& lsum)
{
    half4v r;
    #pragma unroll
    for (int k = 0; k < 4; ++k) {
        float e = sv + dd[k];
        e = fmaxf(e, 0.2f * e);
        float p = ((bits >> k) & 1u) ? __expf(e - cv) : 0.0f;
        _Float16 ph = (_Float16)p;
        lsum += (float)ph;
        r[k] = ph;
    }
    return r;
}

// ---------------------------------------------------------------------------
// Kernel 3 (main): 1024 blocks = 128 row-tiles(64 rows) x 8 j-splits; exactly
// 4 blocks/CU resident (16 waves). Per iter (128 cols): B tile (64x128 fp16,
// 16 KB, XOR-swizzled) + mask (1 KB) + dv (0.5 KB) staged to LDS, 5
// global_load_lds per wave, vmcnt(5) cross-barrier pipeline. All 4 waves
// share the B tile (4x reuse); waves own disjoint 16-row strips.
// ---------------------------------------------------------------------------
__global__ __launch_bounds__(256, 4) void k_main(const unsigned char* __restrict__ mask,
                                                 const _Float16* __restrict__ WhT,
                                                 const float* __restrict__ s,
                                                 const float* __restrict__ c,
                                                 const float* __restrict__ dv,
                                                 float* __restrict__ part)
{
    __shared__ __align__(16) unsigned char sm[2 * BUF_SZ];

    const int tid  = threadIdx.x;
    const int wv   = tid >> 6;
    const int lane = tid & 63;
    const int mrow = lane & 15;        // A-frag row / B-frag feature-in-tile
    const int g    = lane >> 4;        // k-quad
    const int rt   = blockIdx.x & 127;
    const int js   = blockIdx.x >> 7;
    const int i0   = rt * 64;
    const int j0base = js * JRANGE;
    const int arow = i0 + wv * 16 + mrow;

    const float sv = s[arow];
    const float cv = c[arow];

    f32x4 acc[4];
    #pragma unroll
    for (int n = 0; n < 4; ++n) acc[n] = (f32x4){0.f, 0.f, 0.f, 0.f};
    float lsum = 0.f;

    // stage tile `it` into buffer b: exactly 5 global_load_lds per wave
    auto stage = [&](int b, int it) {
        const int j0 = j0base + it * JT;
        unsigned char* base = &sm[b * BUF_SZ];
        #pragma unroll
        for (int q = 0; q < 4; ++q) {
            const int f0 = wv * 16 + q * 4;
            const int f  = f0 + (lane >> 4);
            const int j16 = (lane & 15) ^ (f & 15);       // global-side swizzle
            async16(WhT + (size_t)f * NN + j0 + j16 * 8,
                    base + B_OFF + f0 * 256);
        }
        if (wv == 0)
            async16(mask + (size_t)(i0 + lane) * MROW + (j0 >> 3), base + MK_OFF);
        else if (wv == 1)
            async4(dv + j0 + lane, base + DV_OFF);
        else if (wv == 2)
            async4(dv + j0 + 64 + lane, base + DV_OFF + 256);
        else
            async16(mask + (size_t)(i0 + lane) * MROW + (j0 >> 3), base + DUP_OFF);
    };

    stage(0, 0);
    asm volatile("s_waitcnt vmcnt(0)" ::: "memory");
    __builtin_amdgcn_s_barrier();

    for (int it = 0; it < NIT; ++it) {
        if (it + 1 < NIT) {
            stage((it + 1) & 1, it + 1);                      // prefetch
            asm volatile("s_waitcnt vmcnt(5)" ::: "memory");  // drain tile(it)
        } else {
            asm volatile("s_waitcnt vmcnt(0)" ::: "memory");
        }
        __builtin_amdgcn_s_barrier();                          // tile(it) ready
        asm volatile("" ::: "memory");

        const unsigned char* base = &sm[(it & 1) * BUF_SZ];
        const unsigned long long* mk =
            (const unsigned long long*)(base + MK_OFF + (wv * 16 + mrow) * 16);
        const unsigned long long mv0 = mk[0], mv1 = mk[1];
        const float* dvt = (const float*)(base + DV_OFF);

        #pragma unroll
        for (int cc = 0; cc < 4; ++cc) {
            const unsigned long long mv = (cc < 2) ? mv0 : mv1;
            const unsigned bits =
                (unsigned)(mv >> ((cc & 1) * 32 + g * 8)) & 0xffu;

            f32x4v d0 = *(const f32x4v*)(dvt + cc * 32 + g * 8);
            f32x4v d1 = *(const f32x4v*)(dvt + cc * 32 + g * 8 + 4);
            half4v lo = build4(sv, cv, bits & 15u, d0, lsum);
            half4v hi = build4(sv, cv, bits >> 4,  d1, lsum);
            half8 Af = __builtin_shufflevector(lo, hi, 0, 1, 2, 3, 4, 5, 6, 7);

            const int slot = ((cc * 4 + g) ^ mrow) * 16;      // reader swizzle
            #pragma unroll
            for (int n = 0; n < 4; ++n) {
                half8 B = *(const half8*)(base + B_OFF + (n * 16 + mrow) * 256 + slot);
                acc[n] = __builtin_amdgcn_mfma_f32_16x16x32_f16(Af, B, acc[n], 0, 0, 0);
            }
        }

        if (it + 1 < NIT) {
            asm volatile("" ::: "memory");
            __builtin_amdgcn_s_barrier();   // reads done before next overwrite
        }
    }

    // ---- epilogue: per-wave, no cross-wave combine ----
    float ltot = lsum + __shfl_xor(lsum, 16);
    ltot += __shfl_xor(ltot, 32);

    float* pb = part + (size_t)blockIdx.x * (64 * PROW) + wv * 16 * PROW;
    #pragma unroll
    for (int n = 0; n < 4; ++n)
        #pragma unroll
        for (int r = 0; r < 4; ++r)
            pb[(g * 4 + r) * PROW + n * 16 + mrow] = acc[n][r];
    if (g == 0)
        pb[mrow * PROW + 64] = ltot;
}

// ---------------------------------------------------------------------------
// Kernel 4: combine 8 j-split partials, divide by l, ELU, write out.
// ---------------------------------------------------------------------------
__global__ __launch_bounds__(256) void k_reduce(const float* __restrict__ part,
                                                float* __restrict__ out)
{
    const int rb  = blockIdx.x;
    const int col = threadIdx.x & 63;
    const int r0  = threadIdx.x >> 6;
    #pragma unroll
    for (int rr = 0; rr < 4; ++rr) {
        const int r   = rb * 16 + r0 * 4 + rr;
        const int rtr = r >> 6;
        const int rl  = r & 63;
        float h = 0.f, l = 0.f;
        #pragma unroll
        for (int js = 0; js < 8; ++js) {
            const float* pbase =
                part + ((size_t)(js * 128 + rtr) * 64 + rl) * PROW;
            h += pbase[col];
            l += pbase[64];
        }
        float v = h / l;
        out[(size_t)r * FF + col] = (v > 0.f) ? v : (__expf(v) - 1.0f);
    }
}

extern "C" void kernel_launch(void* const* d_in, const int* in_sizes, int n_in,
                              void* d_out, int out_size, void* d_ws, size_t ws_size,
                              hipStream_t stream)
{
    const float* inp = (const float*)d_in[0];
    const int*   adj = (const int*)d_in[1];
    const float* W   = (const float*)d_in[2];
    const float* a   = (const float*)d_in[3];
    float* out = (float*)d_out;

    char* ws = (char*)d_ws;
    _Float16* WhT = (_Float16*)ws;                           // 64*NN*2 (80 reserved)
    float* s    = (float*)(ws + (size_t)80 * NN * 2);
    float* dv   = s + NN;
    float* c    = dv + NN;
    float* dmp  = c + NN;
    float* part = dmp + 512;                                 // 1024*64*66*4 = 17.3 MB
    unsigned char* mask = (unsigned char*)(part + (size_t)1024 * 64 * PROW);  // 8 MB

    k_pack  <<<(size_t)NN * NN / 8 / 256, 256, 0, stream>>>(adj, mask);
    k_prep  <<<NN / 16, 256, 0, stream>>>(inp, W, a, WhT, s, dv, dmp);
    k_shift <<<32, 256, 0, stream>>>(s, dmp, c);
    k_main  <<<128 * JSPLIT, 256, 0, stream>>>(mask, WhT, s, c, dv, part);
    k_reduce<<<NN / 16, 256, 0, stream>>>(part, out);
}